// Round 9
// baseline (46.433 us; speedup 1.0000x reference)
//
#include <hip/hip_runtime.h>

#define B_ 8
#define C_ 64
#define H_ 192
#define W_ 320
#define HW_ (H_*W_)
#define OUT_ELEMS ((size_t)B_*C_*H_*W_)

#define CSPLIT 8            // channel chunks per batch
#define CPB    (C_/CSPLIT)  // 8 channels per block
#define NTHR   320          // 4 full rows per block; t%80=u-group, t/80=row
#define ROWSPB 4
#define XTILES (H_/ROWSPB)             // 48 row-tiles per (b,chunk)
#define NWG    (XTILES * B_ * CSPLIT)  // 3072
#define NXCD   8

typedef float f32x4 __attribute__((ext_vector_type(4)));

// 8-byte tap-pair with only 4-byte alignment guarantee -> global_load_dwordx2.
struct __attribute__((packed, aligned(4))) fpair { float lo, hi; };

// Per-batch parameter block stored in d_ws as doubles:
// [m00, m01, m02, m10, m12, m20, m22, s, cx] (m11=m21=0 omitted)
__global__ void bev_setup_kernel(const float* __restrict__ h_cam,
                                 const float* __restrict__ p_cam,
                                 const float* __restrict__ fu,
                                 const float* __restrict__ fv,
                                 const int*   __restrict__ plane_h,
                                 double* __restrict__ params,
                                 float*  __restrict__ scales_out,
                                 float*  __restrict__ centers_out) {
    int b = threadIdx.x;
    if (b >= B_) return;
    const double D  = 1e-16;
    const double cu = W_ / 2.0;   // 160
    const double cv = H_ / 2.0;   // 96
    double h   = (double)h_cam[b];
    double p   = (double)p_cam[b];
    double dfu = (double)fu[b];
    double dfv = (double)fv[b];
    double ph  = (double)plane_h[0];
    double h_ref = h - ph;
    double sp = sin(p), cp = cos(p);

    double m00 = cu * cp;
    double m01 = -dfu;
    double m02 = cu * h_ref * sp;
    double m10 = cv * cp - dfv * sp;
    double m12 = h_ref * (dfv * cp + cv * sp);
    double m20 = cp;
    double m22 = h_ref * sp;
    double s   = h / (sp * (cv * cp + dfv * sp) + D);
    double cx  = h * cp / (sp + D);

    double* pp = params + (size_t)b * 10;
    pp[0] = m00; pp[1] = m01; pp[2] = m02;
    pp[3] = m10; pp[4] = m12;
    pp[5] = m20; pp[6] = m22;
    pp[7] = s;   pp[8] = cx;

    scales_out[b] = (float)s;
    centers_out[b*3 + 0] = (float)cx;
    centers_out[b*3 + 1] = 0.0f;
    centers_out[b*3 + 2] = 1.0f;
}

__global__ __launch_bounds__(NTHR)
void bev_main_kernel(const float* __restrict__ x,
                     const double* __restrict__ params,
                     float* __restrict__ out) {
    // XCD-aware bijective swizzle (T1), NWG % 8 == 0.
    const int wg    = blockIdx.x;                      // 0..NWG-1
    const int newid = (wg % NXCD) * (NWG / NXCD) + (wg / NXCD);
    const int bc    = newid / XTILES;                  // 0..63
    const int xt    = newid - bc * XTILES;             // 0..47
    const int b     = bc >> 3;                         // CSPLIT = 8
    const int c0    = (bc & 7) * CPB;

    const int t  = threadIdx.x;
    const int rg = t / 80;            // row within tile (0..3)
    const int u0 = t - rg * 80;       // 0..79; pixels u0 + 80j, j=0..3
    const int v  = xt * ROWSPB + rg;  // output row

    const double* pp = params + (size_t)b * 10;
    const double m00 = pp[0], m01 = pp[1], m02 = pp[2];
    const double m10 = pp[3], m12 = pp[4];
    const double m20 = pp[5], m22 = pp[6];
    const double s   = pp[7], cx  = pp[8];

    // Row-level geometry: t2 and sv depend only on v; su is affine in u.
    const double wx     = cx + s * ((double)(H_/2) - (double)v);
    const double t2     = m20 * wx + m22;
    const double inv_t2 = 1.0 / t2;
    const double sv     = (m10 * wx + m12) * inv_t2;
    const double su_c   = (m00 * wx + m02) * inv_t2;   // constant part
    const double su_k   = m01 * s * inv_t2;            // coeff of (cu - u)

    const bool rowin = (sv >= 0.0) && (sv < (double)(H_-1));
    int v0i = 0;
    float dv0 = 0.f, dv1 = 0.f;
    if (rowin) {
        v0i = (int)sv;                          // sv >= 0
        dv0 = (float)(sv - (double)v0i);
        dv1 = (float)((double)(v0i + 1) - sv);
    }

    // Per-j weights; j-th pixel is u0 + 80j (same row -> lane-adjacent taps
    // are |su_k| elements apart -> few 64B segments per gather instruction).
    float wa[4], wb[4], wc[4], wd[4];
    int   base[4];
    #pragma unroll
    for (int j = 0; j < 4; ++j) {
        const double su = su_c + su_k * ((double)(W_/2) - (double)(u0 + 80*j));
        const bool inr = rowin && (su >= 0.0) && (su < (double)(W_-1));
        int u0i = 0;
        float du0 = 0.f, du1 = 0.f;
        if (inr) {
            u0i = (int)su;
            du0 = (float)(su - (double)u0i);
            du1 = (float)((double)(u0i + 1) - su);
        }
        wa[j] = dv1 * du1;   // (v0, u0)
        wb[j] = dv0 * du1;   // (v1, u0)
        wc[j] = dv1 * du0;   // (v0, u1)
        wd[j] = dv0 * du0;   // (v1, u1)
        base[j] = v0i * W_ + u0i;
    }

    const float* __restrict__ xb = x   + ((size_t)(b * C_ + c0)) * HW_;
    float* __restrict__       ob = out + ((size_t)(b * C_ + c0)) * HW_
                                       + (size_t)v * W_ + (size_t)u0;

    #pragma unroll 2
    for (int c = 0; c < CPB; ++c) {
        const float* __restrict__ xc = xb + (size_t)c * HW_;
        float* __restrict__       oc = ob + (size_t)c * HW_;
        fpair tp[4], bp[4];
        #pragma unroll
        for (int j = 0; j < 4; ++j) {
            tp[j] = *(const fpair*)(xc + base[j]);        // (v0,u0),(v0,u1)
            bp[j] = *(const fpair*)(xc + base[j] + W_);   // (v1,u0),(v1,u1)
        }
        #pragma unroll
        for (int j = 0; j < 4; ++j) {
            const float r = wa[j]*tp[j].lo + wc[j]*tp[j].hi
                          + wb[j]*bp[j].lo + wd[j]*bp[j].hi;
            __builtin_nontemporal_store(r, oc + 80*j);
        }
    }
}

extern "C" void kernel_launch(void* const* d_in, const int* in_sizes, int n_in,
                              void* d_out, int out_size, void* d_ws, size_t ws_size,
                              hipStream_t stream) {
    const float* x     = (const float*)d_in[0];
    const float* h_cam = (const float*)d_in[1];
    const float* p_cam = (const float*)d_in[2];
    const float* fu    = (const float*)d_in[3];
    const float* fv    = (const float*)d_in[4];
    const int*   ph    = (const int*)  d_in[5];

    float* out = (float*)d_out;
    float* scales_out  = out + OUT_ELEMS;        // 8 floats
    float* centers_out = out + OUT_ELEMS + B_;   // 24 floats
    double* params = (double*)d_ws;              // 8 * 10 doubles = 640 B

    bev_setup_kernel<<<1, 64, 0, stream>>>(h_cam, p_cam, fu, fv, ph,
                                           params, scales_out, centers_out);

    bev_main_kernel<<<NWG, NTHR, 0, stream>>>(x, params, out);
}

// Round 10
// 40.511 us; speedup vs baseline: 1.1462x; 1.1462x over previous
//
#include <hip/hip_runtime.h>

#define B_ 8
#define C_ 64
#define H_ 192
#define W_ 320
#define HW_ (H_*W_)
#define OUT_ELEMS ((size_t)B_*C_*H_*W_)

#define CSPLIT 8            // channel chunks per batch
#define CPB    (C_/CSPLIT)  // 8 channels per block
#define CGRP   4            // channels per load-group
#define PIXT   4            // pixels per thread (float4 store)
#define XTILES (HW_/(256*PIXT))        // 60 pixel-tiles per (b,chunk)
#define NWG    (XTILES * B_ * CSPLIT)  // 3840
#define NXCD   8

typedef float f32x4 __attribute__((ext_vector_type(4)));

// 8-byte tap-pair with only 4-byte alignment guarantee -> global_load_dwordx2.
struct __attribute__((packed, aligned(4))) fpair { float lo, hi; };

// Compute the 9 per-batch geometry params (f64). ~40 f64 ops + sin/cos.
__device__ inline void compute_params(const float* h_cam, const float* p_cam,
                                      const float* fu, const float* fv,
                                      const int* plane_h, int b, double* pp) {
    const double D  = 1e-16;
    const double cu = W_ / 2.0;   // 160
    const double cv = H_ / 2.0;   // 96
    double h   = (double)h_cam[b];
    double p   = (double)p_cam[b];
    double dfu = (double)fu[b];
    double dfv = (double)fv[b];
    double ph  = (double)plane_h[0];
    double h_ref = h - ph;
    double sp = sin(p), cp = cos(p);

    pp[0] = cu * cp;                       // m00
    pp[1] = -dfu;                          // m01
    pp[2] = cu * h_ref * sp;               // m02
    pp[3] = cv * cp - dfv * sp;            // m10
    pp[4] = h_ref * (dfv * cp + cv * sp);  // m12
    pp[5] = cp;                            // m20
    pp[6] = h_ref * sp;                    // m22
    pp[7] = h / (sp * (cv * cp + dfv * sp) + D);  // s
    pp[8] = h * cp / (sp + D);                    // cx
}

__global__ __launch_bounds__(256, 4)
void bev_fused_kernel(const float* __restrict__ x,
                      const float* __restrict__ h_cam,
                      const float* __restrict__ p_cam,
                      const float* __restrict__ fu,
                      const float* __restrict__ fv,
                      const int*   __restrict__ plane_h,
                      float* __restrict__ out) {
    // XCD-aware bijective swizzle (T1): XCD k (= wg % 8 dispatch round-robin)
    // gets the contiguous chunk [k*480, (k+1)*480) of logical block ids.
    const int wg    = blockIdx.x;                      // 0..NWG-1
    const int newid = (wg % NXCD) * (NWG / NXCD) + (wg / NXCD);
    const int bc    = newid / XTILES;                  // 0..63
    const int xt    = newid - bc * XTILES;             // 0..59
    const int b     = bc >> 3;                         // CSPLIT = 8
    const int c0    = (bc & 7) * CPB;
    const int pix0  = (xt * 256 + threadIdx.x) * PIXT;
    const int v     = pix0 / W_;                       // 4 | W: all 4 px same row
    const int u     = pix0 - v * W_;

    // Per-block geometry: lane 0 computes, LDS broadcast (saves the separate
    // setup kernel -> one dispatch per replay instead of two).
    __shared__ double pps[9];
    if (threadIdx.x == 0) {
        double tmp[9];
        compute_params(h_cam, p_cam, fu, fv, plane_h, b, tmp);
        #pragma unroll
        for (int i = 0; i < 9; ++i) pps[i] = tmp[i];
    }
    // Block 0 also writes the scales (8) + centers (24) output tail.
    if (wg == 0 && threadIdx.x < B_) {
        double tmp[9];
        compute_params(h_cam, p_cam, fu, fv, plane_h, (int)threadIdx.x, tmp);
        float* scales_out  = out + OUT_ELEMS;
        float* centers_out = out + OUT_ELEMS + B_;
        scales_out[threadIdx.x] = (float)tmp[7];
        centers_out[threadIdx.x*3 + 0] = (float)tmp[8];
        centers_out[threadIdx.x*3 + 1] = 0.0f;
        centers_out[threadIdx.x*3 + 2] = 1.0f;
    }
    __syncthreads();

    const double m00 = pps[0], m01 = pps[1], m02 = pps[2];
    const double m10 = pps[3], m12 = pps[4];
    const double m20 = pps[5], m22 = pps[6];
    const double s   = pps[7], cx  = pps[8];

    // Row-level geometry: t2 and sv depend only on v; su is affine in u.
    const double wx     = cx + s * ((double)(H_/2) - (double)v);
    const double t2     = m20 * wx + m22;
    const double inv_t2 = 1.0 / t2;
    const double sv     = (m10 * wx + m12) * inv_t2;
    const double su_c   = (m00 * wx + m02) * inv_t2;   // constant part
    const double su_k   = m01 * s * inv_t2;            // coeff of (cu - u)

    const bool rowin = (sv >= 0.0) && (sv < (double)(H_-1));
    int v0i = 0;
    float dv0 = 0.f, dv1 = 0.f;
    if (rowin) {
        v0i = (int)sv;                          // sv >= 0
        dv0 = (float)(sv - (double)v0i);
        dv1 = (float)((double)(v0i + 1) - sv);
    }

    float wa[PIXT], wb[PIXT], wc[PIXT], wd[PIXT];
    int   base[PIXT];
    #pragma unroll
    for (int k = 0; k < PIXT; ++k) {
        const double su = su_c + su_k * ((double)(W_/2) - (double)(u + k));
        const bool inr = rowin && (su >= 0.0) && (su < (double)(W_-1));
        int u0i = 0;
        float du0 = 0.f, du1 = 0.f;
        if (inr) {
            u0i = (int)su;
            du0 = (float)(su - (double)u0i);
            du1 = (float)((double)(u0i + 1) - su);
        }
        wa[k] = dv1 * du1;   // (v0, u0)
        wb[k] = dv0 * du1;   // (v1, u0)
        wc[k] = dv1 * du0;   // (v0, u1)
        wd[k] = dv0 * du0;   // (v1, u1)
        base[k] = v0i * W_ + u0i;
    }

    const float* __restrict__ xb = x   + ((size_t)(b * C_ + c0)) * HW_;
    float* __restrict__       ob = out + ((size_t)(b * C_ + c0)) * HW_ + (size_t)pix0;

    // Each pixel's 4 taps = 2 horizontally-adjacent pairs -> 2 dwordx2 gathers.
    #pragma unroll
    for (int g = 0; g < CPB / CGRP; ++g) {
        fpair tp[CGRP][PIXT], bp[CGRP][PIXT];
        #pragma unroll
        for (int c = 0; c < CGRP; ++c) {
            const float* __restrict__ xc = xb + (size_t)(g * CGRP + c) * HW_;
            #pragma unroll
            for (int k = 0; k < PIXT; ++k) {
                tp[c][k] = *(const fpair*)(xc + base[k]);        // (v0,u0),(v0,u1)
                bp[c][k] = *(const fpair*)(xc + base[k] + W_);   // (v1,u0),(v1,u1)
            }
        }
        #pragma unroll
        for (int c = 0; c < CGRP; ++c) {
            f32x4 r;
            r.x = wa[0]*tp[c][0].lo + wc[0]*tp[c][0].hi + wb[0]*bp[c][0].lo + wd[0]*bp[c][0].hi;
            r.y = wa[1]*tp[c][1].lo + wc[1]*tp[c][1].hi + wb[1]*bp[c][1].lo + wd[1]*bp[c][1].hi;
            r.z = wa[2]*tp[c][2].lo + wc[2]*tp[c][2].hi + wb[2]*bp[c][2].lo + wd[2]*bp[c][2].hi;
            r.w = wa[3]*tp[c][3].lo + wc[3]*tp[c][3].hi + wb[3]*bp[c][3].lo + wd[3]*bp[c][3].hi;
            __builtin_nontemporal_store(r, (f32x4*)(ob + (size_t)(g * CGRP + c) * HW_));
        }
    }
}

extern "C" void kernel_launch(void* const* d_in, const int* in_sizes, int n_in,
                              void* d_out, int out_size, void* d_ws, size_t ws_size,
                              hipStream_t stream) {
    const float* x     = (const float*)d_in[0];
    const float* h_cam = (const float*)d_in[1];
    const float* p_cam = (const float*)d_in[2];
    const float* fu    = (const float*)d_in[3];
    const float* fv    = (const float*)d_in[4];
    const int*   ph    = (const int*)  d_in[5];

    bev_fused_kernel<<<NWG, 256, 0, stream>>>(x, h_cam, p_cam, fu, fv, ph,
                                              (float*)d_out);
}

// Round 11
// 39.984 us; speedup vs baseline: 1.1613x; 1.0132x over previous
//
#include <hip/hip_runtime.h>

#define B_ 8
#define C_ 64
#define H_ 192
#define W_ 320
#define HW_ (H_*W_)
#define OUT_ELEMS ((size_t)B_*C_*H_*W_)

#define CSPLIT 16           // channel chunks per batch
#define CPB    (C_/CSPLIT)  // 4 channels per block
#define PIXT   4            // pixels per thread (float4 store)
#define XTILES (HW_/(256*PIXT))        // 60 pixel-tiles per (b,chunk)
#define NWG    (XTILES * B_ * CSPLIT)  // 7680
#define NXCD   8

typedef float f32x4 __attribute__((ext_vector_type(4)));

// 8-byte tap-pair with only 4-byte alignment guarantee -> global_load_dwordx2.
struct __attribute__((packed, aligned(4))) fpair { float lo, hi; };

// Compute the 9 per-batch geometry params (f64). ~40 f64 ops + sin/cos.
__device__ inline void compute_params(const float* h_cam, const float* p_cam,
                                      const float* fu, const float* fv,
                                      const int* plane_h, int b, double* pp) {
    const double D  = 1e-16;
    const double cu = W_ / 2.0;   // 160
    const double cv = H_ / 2.0;   // 96
    double h   = (double)h_cam[b];
    double p   = (double)p_cam[b];
    double dfu = (double)fu[b];
    double dfv = (double)fv[b];
    double ph  = (double)plane_h[0];
    double h_ref = h - ph;
    double sp = sin(p), cp = cos(p);

    pp[0] = cu * cp;                       // m00
    pp[1] = -dfu;                          // m01
    pp[2] = cu * h_ref * sp;               // m02
    pp[3] = cv * cp - dfv * sp;            // m10
    pp[4] = h_ref * (dfv * cp + cv * sp);  // m12
    pp[5] = cp;                            // m20
    pp[6] = h_ref * sp;                    // m22
    pp[7] = h / (sp * (cv * cp + dfv * sp) + D);  // s
    pp[8] = h * cp / (sp + D);                    // cx
}

__global__ __launch_bounds__(256)
void bev_fused_kernel(const float* __restrict__ x,
                      const float* __restrict__ h_cam,
                      const float* __restrict__ p_cam,
                      const float* __restrict__ fu,
                      const float* __restrict__ fv,
                      const int*   __restrict__ plane_h,
                      float* __restrict__ out) {
    // XCD-aware bijective swizzle (T1): XCD k (= wg % 8 dispatch round-robin)
    // gets the contiguous chunk [k*960, (k+1)*960) of logical block ids.
    const int wg    = blockIdx.x;                      // 0..NWG-1
    const int newid = (wg % NXCD) * (NWG / NXCD) + (wg / NXCD);
    const int bc    = newid / XTILES;                  // 0..127
    const int xt    = newid - bc * XTILES;             // 0..59
    const int b     = bc >> 4;                         // CSPLIT = 16
    const int c0    = (bc & 15) * CPB;
    const int pix0  = (xt * 256 + threadIdx.x) * PIXT;
    const int v     = pix0 / W_;                       // 4 | W: all 4 px same row
    const int u     = pix0 - v * W_;

    // Per-block geometry: lane 0 computes, LDS broadcast.
    __shared__ double pps[9];
    if (threadIdx.x == 0) {
        double tmp[9];
        compute_params(h_cam, p_cam, fu, fv, plane_h, b, tmp);
        #pragma unroll
        for (int i = 0; i < 9; ++i) pps[i] = tmp[i];
    }
    // Block 0 also writes the scales (8) + centers (24) output tail.
    if (wg == 0 && threadIdx.x < B_) {
        double tmp[9];
        compute_params(h_cam, p_cam, fu, fv, plane_h, (int)threadIdx.x, tmp);
        float* scales_out  = out + OUT_ELEMS;
        float* centers_out = out + OUT_ELEMS + B_;
        scales_out[threadIdx.x] = (float)tmp[7];
        centers_out[threadIdx.x*3 + 0] = (float)tmp[8];
        centers_out[threadIdx.x*3 + 1] = 0.0f;
        centers_out[threadIdx.x*3 + 2] = 1.0f;
    }
    __syncthreads();

    const double m00 = pps[0], m01 = pps[1], m02 = pps[2];
    const double m10 = pps[3], m12 = pps[4];
    const double m20 = pps[5], m22 = pps[6];
    const double s   = pps[7], cx  = pps[8];

    // Row-level geometry: t2 and sv depend only on v; su is affine in u.
    const double wx     = cx + s * ((double)(H_/2) - (double)v);
    const double t2     = m20 * wx + m22;
    const double inv_t2 = 1.0 / t2;
    const double sv     = (m10 * wx + m12) * inv_t2;
    const double su_c   = (m00 * wx + m02) * inv_t2;   // constant part
    const double su_k   = m01 * s * inv_t2;            // coeff of (cu - u)

    const bool rowin = (sv >= 0.0) && (sv < (double)(H_-1));
    int v0i = 0;
    float dv0 = 0.f, dv1 = 0.f;
    if (rowin) {
        v0i = (int)sv;                          // sv >= 0
        dv0 = (float)(sv - (double)v0i);
        dv1 = (float)((double)(v0i + 1) - sv);
    }

    float wa[PIXT], wb[PIXT], wc[PIXT], wd[PIXT];
    int   base[PIXT];
    #pragma unroll
    for (int k = 0; k < PIXT; ++k) {
        const double su = su_c + su_k * ((double)(W_/2) - (double)(u + k));
        const bool inr = rowin && (su >= 0.0) && (su < (double)(W_-1));
        int u0i = 0;
        float du0 = 0.f, du1 = 0.f;
        if (inr) {
            u0i = (int)su;
            du0 = (float)(su - (double)u0i);
            du1 = (float)((double)(u0i + 1) - su);
        }
        wa[k] = dv1 * du1;   // (v0, u0)
        wb[k] = dv0 * du1;   // (v1, u0)
        wc[k] = dv1 * du0;   // (v0, u1)
        wd[k] = dv0 * du0;   // (v1, u1)
        base[k] = v0i * W_ + u0i;
    }

    const float* __restrict__ xb = x   + ((size_t)(b * C_ + c0)) * HW_;
    float* __restrict__       ob = out + ((size_t)(b * C_ + c0)) * HW_ + (size_t)pix0;

    // 4 channels: issue all 32 tap-pair gathers, then combine + NT store.
    fpair tp[CPB][PIXT], bp[CPB][PIXT];
    #pragma unroll
    for (int c = 0; c < CPB; ++c) {
        const float* __restrict__ xc = xb + (size_t)c * HW_;
        #pragma unroll
        for (int k = 0; k < PIXT; ++k) {
            tp[c][k] = *(const fpair*)(xc + base[k]);        // (v0,u0),(v0,u1)
            bp[c][k] = *(const fpair*)(xc + base[k] + W_);   // (v1,u0),(v1,u1)
        }
    }
    #pragma unroll
    for (int c = 0; c < CPB; ++c) {
        f32x4 r;
        r.x = wa[0]*tp[c][0].lo + wc[0]*tp[c][0].hi + wb[0]*bp[c][0].lo + wd[0]*bp[c][0].hi;
        r.y = wa[1]*tp[c][1].lo + wc[1]*tp[c][1].hi + wb[1]*bp[c][1].lo + wd[1]*bp[c][1].hi;
        r.z = wa[2]*tp[c][2].lo + wc[2]*tp[c][2].hi + wb[2]*bp[c][2].lo + wd[2]*bp[c][2].hi;
        r.w = wa[3]*tp[c][3].lo + wc[3]*tp[c][3].hi + wb[3]*bp[c][3].lo + wd[3]*bp[c][3].hi;
        __builtin_nontemporal_store(r, (f32x4*)(ob + (size_t)c * HW_));
    }
}

extern "C" void kernel_launch(void* const* d_in, const int* in_sizes, int n_in,
                              void* d_out, int out_size, void* d_ws, size_t ws_size,
                              hipStream_t stream) {
    const float* x     = (const float*)d_in[0];
    const float* h_cam = (const float*)d_in[1];
    const float* p_cam = (const float*)d_in[2];
    const float* fu    = (const float*)d_in[3];
    const float* fv    = (const float*)d_in[4];
    const int*   ph    = (const int*)  d_in[5];

    bev_fused_kernel<<<NWG, 256, 0, stream>>>(x, h_cam, p_cam, fu, fv, ph,
                                              (float*)d_out);
}